// Round 4
// baseline (9196.604 us; speedup 1.0000x reference)
//
#include <hip/hip_runtime.h>
#include <math.h>

// Problem constants
#define Bb    64
#define Cc    100
#define Ff    2048
#define Tt    32
#define Hh    300
#define COMBc 2648
#define KP    2704   // COMB padded to 13*208 (gate GEMM k-splits)
#define N4P   1216   // 4*H=1200 padded to 19*64
#define NGATE 1200
#define KPP   2368   // 2048+300 padded to 296*8
#define NPPP  384    // 300 padded to 6*64
#define KOP   304    // 300 padded to 38*8
#define NHP   640    // 2*300 padded to 10*64
#define BOSi  1
#define GRIDN 256
#define NTHR  256

__device__ __forceinline__ float sigmf_(float x){ return 1.0f/(1.0f + expf(-x)); }

__device__ __forceinline__ void fma16_(const float4 av, const float4 bv, float acc[4][4]){
    acc[0][0] += av.x*bv.x; acc[0][1] += av.x*bv.y; acc[0][2] += av.x*bv.z; acc[0][3] += av.x*bv.w;
    acc[1][0] += av.y*bv.x; acc[1][1] += av.y*bv.y; acc[1][2] += av.y*bv.z; acc[1][3] += av.y*bv.w;
    acc[2][0] += av.z*bv.x; acc[2][1] += av.z*bv.y; acc[2][2] += av.z*bv.z; acc[2][3] += av.z*bv.w;
    acc[3][0] += av.w*bv.x; acc[3][1] += av.w*bv.y; acc[3][2] += av.w*bv.z; acc[3][3] += av.w*bv.w;
}

// Manual grid barrier. bar[0]=arrival counter, bar[1]=generation.
// Release fence before arrival, acquire fence after exit (all threads) so
// per-XCD L2s are written back / invalidated — replicates kernel-boundary
// coherence inside the persistent kernel.
__device__ __forceinline__ void gsync(unsigned* bar)
{
    __syncthreads();
    __threadfence();
    if (threadIdx.x == 0) {
        unsigned g = __hip_atomic_load(&bar[1], __ATOMIC_RELAXED, __HIP_MEMORY_SCOPE_AGENT);
        unsigned old = __hip_atomic_fetch_add(&bar[0], 1u, __ATOMIC_ACQ_REL, __HIP_MEMORY_SCOPE_AGENT);
        if (old == GRIDN - 1) {
            __hip_atomic_store(&bar[0], 0u, __ATOMIC_RELAXED, __HIP_MEMORY_SCOPE_AGENT);
            __hip_atomic_fetch_add(&bar[1], 1u, __ATOMIC_RELEASE, __HIP_MEMORY_SCOPE_AGENT);
        } else {
            while (__hip_atomic_load(&bar[1], __ATOMIC_ACQUIRE, __HIP_MEMORY_SCOPE_AGENT) == g) {
                __builtin_amdgcn_s_sleep(2);
            }
        }
    }
    __syncthreads();
    __threadfence();
}

// Software-pipelined 64x64 GEMM tile: 8-row K-slices, register prefetch of the
// next slice's staging while computing the current one from LDS.
template <typename LA, typename LB>
__device__ __forceinline__ void gemm64(int KB, LA loadA, LB loadB,
                                       float* As, float* Bs, float acc[4][4], int tid)
{
    const int tx = tid & 15, ty = tid >> 4;
    float a0 = loadA(0, tid), a1 = loadA(0, tid + 256);
    float b0 = loadB(0, tid), b1 = loadB(0, tid + 256);
    for (int kb = 0; kb < KB; kb++) {
        __syncthreads();
        As[tid] = a0; As[tid + 256] = a1;
        Bs[tid] = b0; Bs[tid + 256] = b1;
        __syncthreads();
        if (kb + 1 < KB) {
            a0 = loadA(kb+1, tid); a1 = loadA(kb+1, tid + 256);
            b0 = loadB(kb+1, tid); b1 = loadB(kb+1, tid + 256);
        }
#pragma unroll
        for (int kk = 0; kk < 8; kk++) {
            float4 av = *(const float4*)&As[kk*64 + ty*4];
            float4 bv = *(const float4*)&Bs[kk*64 + tx*4];
            fma16_(av, bv, acc);
        }
    }
}

struct MonsterArgs {
    const float *enc, *emb; const int* caps;
    const float *Wh0,*bh0,*Wc0,*bc0,*We_enc,*We_hid,*be;
    const float *Wi,*bi,*Wf,*bf,*Wo,*bo,*Wg,*bg;
    const float *Wcp,*bcp,*Whp,*bhp,*Wop,*bop;
    float* out;
    float *W4p,*Wpp,*Wopp,*Whc,*b4,*bp,*bhc,*e_enc,*hT,*ctxT,*E,*cst,*attnbuf,
          *part,*parth,*ppart,*tmpT,*meanT;
    unsigned* bar;
};

// energy + softmax for step slot+1; h of current step in hbuf[0..299].
__device__ void attn_softmax2(int b, int slot, const float* e_enc,
                              const float* We_hid, float bev,
                              const float* hbuf, float* red, float* attnbuf)
{
    const int tid = threadIdx.x;
    float p = hbuf[tid]*We_hid[tid];
    if (tid + 256 < Hh) p += hbuf[tid+256]*We_hid[tid+256];
    red[tid] = p;
    __syncthreads();
    for (int s = 128; s > 0; s >>= 1) {
        if (tid < s) red[tid] += red[tid + s];
        __syncthreads();
    }
    const float eh = red[0] + bev;
    if (tid < 64) {
        float v0 = e_enc[b*Cc + tid] + eh;
        float v1 = (tid + 64 < Cc) ? (e_enc[b*Cc + tid + 64] + eh) : -1e30f;
        float m = fmaxf(v0, v1);
        for (int o = 32; o; o >>= 1) m = fmaxf(m, __shfl_xor(m, o));
        float e0 = expf(v0 - m);
        float e1 = (tid + 64 < Cc) ? expf(v1 - m) : 0.0f;
        float s = e0 + e1;
        for (int o = 32; o; o >>= 1) s += __shfl_xor(s, o);
        float inv = 1.0f / s;
        attnbuf[slot*8192 + b*128 + tid]      = e0 * inv;
        attnbuf[slot*8192 + b*128 + tid + 64] = e1 * inv;
    }
    __syncthreads();
}

__global__ void k_zero(unsigned* bar)
{
    if (threadIdx.x < 16) bar[threadIdx.x] = 0u;
}

__global__ __launch_bounds__(NTHR, 2) void monster(MonsterArgs P)
{
    const int bid = blockIdx.x, tid = threadIdx.x;
    unsigned* bar = P.bar;
    __shared__ float smem[1120];
    float* As   = smem;
    float* Bs   = smem + 512;
    float* hbuf = smem;          // phase-local reuse
    float* red  = smem + 320;
    float* sA   = smem;

    // ================= PHASE 0: pack weights + init (independent tasks) ======
    {
        // ---- weight packing (grid-stride) ----
        const int T0 = KP*N4P, T1 = KPP*NPPP, T2 = KOP*NPPP, T3 = Ff*NHP;
        const int total = T0 + T1 + T2 + T3 + N4P + NPPP + NHP;
        for (int idx = bid*NTHR + tid; idx < total; idx += GRIDN*NTHR) {
            int i = idx;
            if (i < T0) {
                int j = i / N4P, n = i % N4P, c = n >> 2, g = n & 3;
                float v = 0.0f;
                if (j < COMBc && n < NGATE) {
                    const float* W = (g==0)?P.Wi:(g==1)?P.Wf:(g==2)?P.Wo:P.Wg;
                    v = W[j*Hh + c];
                }
                P.W4p[i] = v; continue;
            }
            i -= T0;
            if (i < T1) {
                int j = i / NPPP, n = i % NPPP;
                float v = 0.0f;
                if (n < Hh) {
                    if (j < Ff) v = P.Wcp[j*Hh + n];
                    else if (j < Ff+Hh) v = P.Whp[(j-Ff)*Hh + n];
                }
                P.Wpp[i] = v; continue;
            }
            i -= T1;
            if (i < T2) {
                int j = i / NPPP, n = i % NPPP;
                P.Wopp[i] = (j < Hh && n < Hh) ? P.Wop[j*Hh + n] : 0.0f;
                continue;
            }
            i -= T2;
            if (i < T3) {
                int j = i / NHP, n = i % NHP, c = n >> 1, g = n & 1;
                P.Whc[i] = (c < Hh) ? (g ? P.Wc0[j*Hh + c] : P.Wh0[j*Hh + c]) : 0.0f;
                continue;
            }
            i -= T3;
            if (i < N4P) {
                int c = i >> 2, g = i & 3;
                float v = 0.0f;
                if (c < Hh) {
                    const float* bb = (g==0)?P.bi:(g==1)?P.bf:(g==2)?P.bo:P.bg;
                    v = bb[c];
                }
                P.b4[i] = v; continue;
            }
            i -= N4P;
            if (i < NPPP) { P.bp[i] = (i < Hh) ? (P.bcp[i] + P.bhp[i]) : 0.0f; continue; }
            i -= NPPP;
            { int c = i >> 1, g = i & 1;
              P.bhc[i] = (c < Hh) ? (g ? P.bc0[c] : P.bh0[c]) : 0.0f; }
        }
        // ---- meanT[f][b]: 256 blocks = (4 f-tiles of 512, 64 b) ----
        {
            const int b = bid & 63, ft = bid >> 6;
            for (int f = ft*512 + tid; f < ft*512 + 512; f += NTHR) {
                const float* pe = P.enc + (b*Cc)*Ff + f;
                float s = 0.0f;
#pragma unroll 10
                for (int c = 0; c < Cc; c++) s += pe[c*Ff];
                P.meanT[f*64 + b] = s * (1.0f/Cc);
            }
        }
        // ---- e_enc[b][c]: block = (b, c-group of 25), wave per c ----
        {
            const int b = bid & 63, cgp = bid >> 6;
            const int w = tid >> 6, lane = tid & 63;
            for (int c = cgp*25 + w; c < cgp*25 + 25; c += 4) {
                const float* p = P.enc + (b*Cc + c)*Ff;
                float s = 0.0f;
                for (int k = lane; k < Ff; k += 64) s += p[k]*P.We_enc[k];
                for (int o = 32; o; o >>= 1) s += __shfl_xor(s, o);
                if (lane == 0) P.e_enc[b*Cc + c] = s;
            }
        }
        // ---- embedding gather E[t][j][b] ----
        for (int idx = bid*NTHR + tid; idx < (Tt-1)*Hh*Bb; idx += GRIDN*NTHR) {
            const int j = idx % Hh;
            const int bt = idx / Hh;
            const int b = bt / (Tt-1), t = bt % (Tt-1);
            P.E[(t*Hh + j)*64 + b] = P.emb[(long)P.caps[b*Tt + t]*Hh + j];
        }
        // ---- out[:,0,:] = embedding[BOS] ----
        for (int idx = bid*NTHR + tid; idx < Bb*Hh; idx += GRIDN*NTHR) {
            const int b = idx / Hh, j = idx % Hh;
            P.out[(b*Tt)*Hh + j] = P.emb[(long)BOSi*Hh + j];
        }
    }
    gsync(bar);

    // ================= PHASE 1: h0/c0 GEMM (meanT @ Whc), 80 units ===========
    if (bid < 80) {
        const int ks = bid & 7, nt = bid >> 3;
        const int n0 = nt*64, k0 = ks*256;
        float acc[4][4] = {};
        auto loadA = [&](int kb, int idx) -> float {
            int j = k0 + kb*8 + (idx >> 6);
            return P.meanT[j*64 + (idx & 63)];
        };
        auto loadB = [&](int kb, int idx) -> float {
            int j = k0 + kb*8 + (idx >> 6);
            return P.Whc[j*NHP + n0 + (idx & 63)];
        };
        gemm64(32, loadA, loadB, As, Bs, acc, tid);
        const int tx = tid & 15, ty = tid >> 4;
#pragma unroll
        for (int i = 0; i < 4; i++)
            *(float4*)&P.parth[(ks*64 + ty*4 + i)*NHP + n0 + tx*4]
                = make_float4(acc[i][0], acc[i][1], acc[i][2], acc[i][3]);
    }
    gsync(bar);

    // ================= PHASE 2: h0/c0 epilogue + softmax for step 1 ==========
    if (bid < 64) {
        const int b = bid;
        for (int col = tid; col < Hh; col += NTHR) {
            float sh = P.bhc[2*col], sc = P.bhc[2*col+1];
            for (int ks = 0; ks < 8; ks++) {
                const float2 v = *(const float2*)&P.parth[(ks*64 + b)*NHP + 2*col];
                sh += v.x; sc += v.y;
            }
            float h = tanhf(sh);
            P.cst[b*Hh + col] = tanhf(sc);
            P.hT[(0*Hh + col)*64 + b] = h;
            hbuf[col] = h;
        }
        __syncthreads();
        attn_softmax2(b, 0, P.e_enc, P.We_hid, P.be[0], hbuf, red, P.attnbuf);
    }
    gsync(bar);

    // ================= RECURRENT LOOP ========================================
    for (int t = 1; t < Tt; t++) {
        // ---- ctx: 128 units = (b, half-of-F), float4 per thread ----
        if (bid < 128) {
            const int b = bid & 63, fh = bid >> 6;
            if (tid < Cc) sA[tid] = P.attnbuf[(t-1)*8192 + b*128 + tid];
            __syncthreads();
            const int f = fh*1024 + tid*4;
            const float* pe = P.enc + (b*Cc)*Ff + f;
            float4 a = make_float4(0.f,0.f,0.f,0.f);
#pragma unroll 10
            for (int c = 0; c < Cc; c++) {
                const float w0 = sA[c];
                const float4 v = *(const float4*)&pe[c*Ff];
                a.x += w0*v.x; a.y += w0*v.y; a.z += w0*v.z; a.w += w0*v.w;
            }
            float* dst = P.ctxT + ((t-1)*Ff + f)*64 + b;
            dst[0] = a.x; dst[64] = a.y; dst[128] = a.z; dst[192] = a.w;
            __syncthreads();
        }
        gsync(bar);

        // ---- gate GEMM: 247 units = (19 n-tiles, 13 k-splits of 208) ----
        if (bid < 247) {
            const int ks = bid % 13, nt = bid / 13;
            const int n0 = nt*64, k0 = ks*208;
            const float* Esrc = P.E    + (t-1)*Hh*64;
            const float* hsrc = P.hT   + (t-1)*Hh*64;
            const float* csrc = P.ctxT + (t-1)*Ff*64;
            float acc[4][4] = {};
            auto loadA = [&](int kb, int idx) -> float {
                int kk = idx >> 6, bb = idx & 63;
                int j = k0 + kb*8 + kk;
                if (j < Hh)        return Esrc[j*64 + bb];
                if (j < 2*Hh)      return hsrc[(j-Hh)*64 + bb];
                if (j < COMBc)     return csrc[(j-2*Hh)*64 + bb];
                return 0.0f;
            };
            auto loadB = [&](int kb, int idx) -> float {
                int j = k0 + kb*8 + (idx >> 6);
                return P.W4p[j*N4P + n0 + (idx & 63)];
            };
            gemm64(26, loadA, loadB, As, Bs, acc, tid);
            const int tx = tid & 15, ty = tid >> 4;
#pragma unroll
            for (int i = 0; i < 4; i++)
                *(float4*)&P.part[(ks*64 + ty*4 + i)*N4P + n0 + tx*4]
                    = make_float4(acc[i][0], acc[i][1], acc[i][2], acc[i][3]);
        }
        gsync(bar);

        // ---- LSTM cell + softmax for next step: 64 units ----
        if (bid < 64) {
            const int b = bid;
            for (int col = tid; col < Hh; col += NTHR) {
                float4 s = ((const float4*)P.b4)[col];
                for (int ks = 0; ks < 13; ks++) {
                    const float4 v = ((const float4*)(P.part + (ks*64 + b)*N4P))[col];
                    s.x += v.x; s.y += v.y; s.z += v.z; s.w += v.w;
                }
                float ig = sigmf_(s.x), fg = sigmf_(s.y), og = sigmf_(s.z), gg = tanhf(s.w);
                float cn = fg*P.cst[b*Hh + col] + ig*gg;
                P.cst[b*Hh + col] = cn;
                float h = og*tanhf(cn);
                P.hT[(t*Hh + col)*64 + b] = h;
                hbuf[col] = h;
            }
            __syncthreads();
            attn_softmax2(b, t, P.e_enc, P.We_hid, P.be[0], hbuf, red, P.attnbuf);
        }
        gsync(bar);
    }

    // ================= PRED A: [ctx_t | h_t] @ [Wcp;Whp], 744 units ==========
    for (int u = bid; u < 744; u += GRIDN) {
        const int nt = u % 6, ti = (u/6) % 31, ks = u / 186;
        const int n0 = nt*64, k0 = ks*592;
        const float* csrc = P.ctxT + ti*Ff*64;
        const float* hsrc = P.hT + (ti+1)*Hh*64;
        float acc[4][4] = {};
        auto loadA = [&](int kb, int idx) -> float {
            int kk = idx >> 6, bb = idx & 63;
            int j = k0 + kb*8 + kk;
            if (j < Ff)      return csrc[j*64 + bb];
            if (j < Ff+Hh)   return hsrc[(j-Ff)*64 + bb];
            return 0.0f;
        };
        auto loadB = [&](int kb, int idx) -> float {
            int j = k0 + kb*8 + (idx >> 6);
            return P.Wpp[j*NPPP + n0 + (idx & 63)];
        };
        gemm64(74, loadA, loadB, As, Bs, acc, tid);
        const int tx = tid & 15, ty = tid >> 4;
#pragma unroll
        for (int j = 0; j < 4; j++)
            *(float4*)&P.ppart[((ks*31 + ti)*NPPP + n0 + tx*4 + j)*64 + ty*4]
                = make_float4(acc[0][j], acc[1][j], acc[2][j], acc[3][j]);
    }
    gsync(bar);

    // ================= PRED A2: reduce + emb + bias -> tmpT ==================
    for (int idx = bid*NTHR + tid; idx < 31*KOP*64; idx += GRIDN*NTHR) {
        const int ti = idx / (KOP*64);
        const int r = idx % (KOP*64);
        const int j = r / 64, b = r % 64;
        float v = 0.0f;
        if (j < Hh) {
            v = P.E[(ti*Hh + j)*64 + b] + P.bp[j];
            for (int ks = 0; ks < 4; ks++)
                v += P.ppart[((ks*31 + ti)*NPPP + j)*64 + b];
        }
        P.tmpT[idx] = v;
    }
    gsync(bar);

    // ================= PRED B: tmp @ Wop + bop -> out, 186 units =============
    if (bid < 186) {
        const int nt = bid % 6, ti = bid / 6;
        const int n0 = nt*64;
        const float* Asrc = P.tmpT + ti*KOP*64;
        float acc[4][4] = {};
        auto loadA = [&](int kb, int idx) -> float {
            int j = kb*8 + (idx >> 6);
            return Asrc[j*64 + (idx & 63)];
        };
        auto loadB = [&](int kb, int idx) -> float {
            int j = kb*8 + (idx >> 6);
            return P.Wopp[j*NPPP + n0 + (idx & 63)];
        };
        gemm64(38, loadA, loadB, As, Bs, acc, tid);
        const int tx = tid & 15, ty = tid >> 4;
#pragma unroll
        for (int i = 0; i < 4; i++) {
            const int b = ty*4 + i;
#pragma unroll
            for (int j = 0; j < 4; j++) {
                const int n = n0 + tx*4 + j;
                if (n < Hh)
                    P.out[(b*Tt + (ti+1))*Hh + n] = acc[i][j] + P.bop[n];
            }
        }
    }
}

// ---------------------------------------------------------------------------
extern "C" void kernel_launch(void* const* d_in, const int* in_sizes, int n_in,
                              void* d_out, int out_size, void* d_ws, size_t ws_size,
                              hipStream_t stream)
{
    MonsterArgs P;
    P.enc    = (const float*)d_in[0];
    P.caps   = (const int*)  d_in[1];
    P.emb    = (const float*)d_in[2];
    P.Wh0    = (const float*)d_in[3];
    P.bh0    = (const float*)d_in[4];
    P.Wc0    = (const float*)d_in[5];
    P.bc0    = (const float*)d_in[6];
    P.We_enc = (const float*)d_in[7];
    P.We_hid = (const float*)d_in[8];
    P.be     = (const float*)d_in[9];
    P.Wi     = (const float*)d_in[10];
    P.bi     = (const float*)d_in[11];
    P.Wf     = (const float*)d_in[12];
    P.bf     = (const float*)d_in[13];
    P.Wo     = (const float*)d_in[14];
    P.bo     = (const float*)d_in[15];
    P.Wg     = (const float*)d_in[16];
    P.bg     = (const float*)d_in[17];
    P.Wcp    = (const float*)d_in[18];
    P.bcp    = (const float*)d_in[19];
    P.Whp    = (const float*)d_in[20];
    P.bhp    = (const float*)d_in[21];
    P.Wop    = (const float*)d_in[22];
    P.bop    = (const float*)d_in[23];
    P.out    = (float*)d_out;

    float* w = (float*)d_ws;
    P.bar   = (unsigned*)w; w += 64;     // barrier state (own cacheline)
    P.W4p   = w; w += KP*N4P;        // 3,288,064
    P.Wpp   = w; w += KPP*NPPP;      //   909,312
    P.Wopp  = w; w += KOP*NPPP;      //   116,736
    P.b4    = w; w += N4P;
    P.bp    = w; w += NPPP;
    P.bhc   = w; w += NHP;
    P.e_enc = w; w += Bb*Cc;
    P.hT    = w; w += Tt*Hh*64;      //   614,400
    P.ctxT  = w; w += (Tt-1)*Ff*64;  // 4,063,232
    P.E     = w; w += (Tt-1)*Hh*64;  //   595,200
    P.cst   = w; w += Bb*Hh;
    P.attnbuf = w; w += Tt*64*128;   //   262,144
    P.part  = w; w += 16*Bb*N4P;     // 1,245,184  (13 used; parth aliases pre-loop)
    P.ppart = w; w += 4*31*NPPP*64;  // 3,047,424  (Whc aliases: used only pre-loop)
    P.tmpT  = w; w += 31*KOP*64;     //   603,136  (meanT aliases: used only pre-loop)
    P.parth = P.part;                // 8*64*640 = 327,680 <= part
    P.Whc   = P.ppart;               // 2048*640 = 1,310,720 <= ppart
    P.meanT = P.tmpT;                // 2048*64  = 131,072 <= tmpT
    (void)ws_size; (void)in_sizes; (void)n_in; (void)out_size;

    k_zero<<<1, 64, 0, stream>>>(P.bar);
    monster<<<GRIDN, NTHR, 0, stream>>>(P);
}

// Round 5
// 3680.241 us; speedup vs baseline: 2.4989x; 2.4989x over previous
//
#include <hip/hip_runtime.h>
#include <math.h>

// Problem constants
#define Bb    64
#define Cc    100
#define Ff    2048
#define Tt    32
#define Hh    300
#define COMBc 2648
#define KP    2704   // COMB padded to 13*208 (gate GEMM k-splits)
#define N4P   1216   // 4*H=1200 padded to 19*64
#define NGATE 1200
#define KPP   2368   // 2048+300 padded to 296*8
#define NPPP  384    // 300 padded to 6*64
#define KOP   304    // 300 padded to 38*8
#define NHP   640    // 2*300 padded to 10*64
#define BOSi  1
#define GRIDN 256
#define NTHR  256

__device__ __forceinline__ float sigmf_(float x){ return 1.0f/(1.0f + expf(-x)); }

// Coherent (agent-scope, LLC) accessors for cross-block activation traffic.
// Relaxed: no cache-invalidate/writeback side effects; the access itself
// bypasses the non-coherent per-XCD L2.
__device__ __forceinline__ float cload(const float* p){
    return __hip_atomic_load(p, __ATOMIC_RELAXED, __HIP_MEMORY_SCOPE_AGENT);
}
__device__ __forceinline__ void cstore(float* p, float v){
    __hip_atomic_store(p, v, __ATOMIC_RELAXED, __HIP_MEMORY_SCOPE_AGENT);
}

__device__ __forceinline__ void fma16_(const float4 av, const float4 bv, float acc[4][4]){
    acc[0][0] += av.x*bv.x; acc[0][1] += av.x*bv.y; acc[0][2] += av.x*bv.z; acc[0][3] += av.x*bv.w;
    acc[1][0] += av.y*bv.x; acc[1][1] += av.y*bv.y; acc[1][2] += av.y*bv.z; acc[1][3] += av.y*bv.w;
    acc[2][0] += av.z*bv.x; acc[2][1] += av.z*bv.y; acc[2][2] += av.z*bv.z; acc[2][3] += av.z*bv.w;
    acc[3][0] += av.w*bv.x; acc[3][1] += av.w*bv.y; acc[3][2] += av.w*bv.z; acc[3][3] += av.w*bv.w;
}

// LIGHT grid barrier: relaxed spin (NO acquire -> no buffer_inv, L2 stays
// warm). Arrival is a RELEASE fetch-add so each block's prior stores (incl.
// coherent ones, via the vmcnt drain) are LLC-visible before the generation
// bump can be observed.
__device__ __forceinline__ void gsync_light(unsigned* bar)
{
    __syncthreads();
    if (threadIdx.x == 0) {
        unsigned g = __hip_atomic_load(&bar[1], __ATOMIC_RELAXED, __HIP_MEMORY_SCOPE_AGENT);
        unsigned old = __hip_atomic_fetch_add(&bar[0], 1u, __ATOMIC_RELEASE, __HIP_MEMORY_SCOPE_AGENT);
        if (old == GRIDN - 1) {
            __hip_atomic_store(&bar[0], 0u, __ATOMIC_RELAXED, __HIP_MEMORY_SCOPE_AGENT);
            __hip_atomic_store(&bar[1], g + 1u, __ATOMIC_RELAXED, __HIP_MEMORY_SCOPE_AGENT);
        } else {
            while (__hip_atomic_load(&bar[1], __ATOMIC_RELAXED, __HIP_MEMORY_SCOPE_AGENT) == g)
                __builtin_amdgcn_s_sleep(2);
        }
    }
    __syncthreads();
}

// HEAVY grid barrier: full release+acquire fences (wbl2 + inv), used only at
// one-time phase boundaries where bulk cached data changes ownership.
__device__ __forceinline__ void gsync_heavy(unsigned* bar)
{
    __syncthreads();
    if (threadIdx.x == 0) {
        __threadfence();   // release: write back dirty L2
        unsigned g = __hip_atomic_load(&bar[1], __ATOMIC_RELAXED, __HIP_MEMORY_SCOPE_AGENT);
        unsigned old = __hip_atomic_fetch_add(&bar[0], 1u, __ATOMIC_RELEASE, __HIP_MEMORY_SCOPE_AGENT);
        if (old == GRIDN - 1) {
            __hip_atomic_store(&bar[0], 0u, __ATOMIC_RELAXED, __HIP_MEMORY_SCOPE_AGENT);
            __hip_atomic_store(&bar[1], g + 1u, __ATOMIC_RELAXED, __HIP_MEMORY_SCOPE_AGENT);
        } else {
            while (__hip_atomic_load(&bar[1], __ATOMIC_RELAXED, __HIP_MEMORY_SCOPE_AGENT) == g)
                __builtin_amdgcn_s_sleep(2);
        }
        __threadfence();   // acquire: invalidate stale cached copies
    }
    __syncthreads();
}

// Software-pipelined 64x64 GEMM tile: 8-row K-slices, register prefetch of the
// next slice's staging while computing the current one from LDS.
template <typename LA, typename LB>
__device__ __forceinline__ void gemm64(int KB, LA loadA, LB loadB,
                                       float* As, float* Bs, float acc[4][4], int tid)
{
    const int tx = tid & 15, ty = tid >> 4;
    float a0 = loadA(0, tid), a1 = loadA(0, tid + 256);
    float b0 = loadB(0, tid), b1 = loadB(0, tid + 256);
    for (int kb = 0; kb < KB; kb++) {
        __syncthreads();
        As[tid] = a0; As[tid + 256] = a1;
        Bs[tid] = b0; Bs[tid + 256] = b1;
        __syncthreads();
        if (kb + 1 < KB) {
            a0 = loadA(kb+1, tid); a1 = loadA(kb+1, tid + 256);
            b0 = loadB(kb+1, tid); b1 = loadB(kb+1, tid + 256);
        }
#pragma unroll
        for (int kk = 0; kk < 8; kk++) {
            float4 av = *(const float4*)&As[kk*64 + ty*4];
            float4 bv = *(const float4*)&Bs[kk*64 + tx*4];
            fma16_(av, bv, acc);
        }
    }
}

struct MonsterArgs {
    const float *enc, *emb; const int* caps;
    const float *Wh0,*bh0,*Wc0,*bc0,*We_enc,*We_hid,*be;
    const float *Wi,*bi,*Wf,*bf,*Wo,*bo,*Wg,*bg;
    const float *Wcp,*bcp,*Whp,*bhp,*Wop,*bop;
    float* out;
    float *W4p,*Wpp,*Wopp,*Whc,*b4,*bp,*bhc,*e_enc,*hT,*ctxT,*E,*cst,*attnbuf,
          *part,*parth,*ppart,*tmpT,*meanT;
    unsigned* bar;
};

// energy + softmax for step slot+1; h of current step in hbuf[0..299].
// attnbuf written COHERENT (read next phase by ctx blocks on other XCDs).
__device__ void attn_softmax2(int b, int slot, const float* e_enc,
                              const float* We_hid, float bev,
                              const float* hbuf, float* red, float* attnbuf)
{
    const int tid = threadIdx.x;
    float p = hbuf[tid]*We_hid[tid];
    if (tid + 256 < Hh) p += hbuf[tid+256]*We_hid[tid+256];
    red[tid] = p;
    __syncthreads();
    for (int s = 128; s > 0; s >>= 1) {
        if (tid < s) red[tid] += red[tid + s];
        __syncthreads();
    }
    const float eh = red[0] + bev;
    if (tid < 64) {
        float v0 = e_enc[b*Cc + tid] + eh;
        float v1 = (tid + 64 < Cc) ? (e_enc[b*Cc + tid + 64] + eh) : -1e30f;
        float m = fmaxf(v0, v1);
        for (int o = 32; o; o >>= 1) m = fmaxf(m, __shfl_xor(m, o));
        float e0 = expf(v0 - m);
        float e1 = (tid + 64 < Cc) ? expf(v1 - m) : 0.0f;
        float s = e0 + e1;
        for (int o = 32; o; o >>= 1) s += __shfl_xor(s, o);
        float inv = 1.0f / s;
        cstore(&attnbuf[slot*8192 + b*128 + tid],      e0 * inv);
        cstore(&attnbuf[slot*8192 + b*128 + tid + 64], e1 * inv);
    }
    __syncthreads();
}

__global__ void k_zero(unsigned* bar)
{
    if (threadIdx.x < 16) bar[threadIdx.x] = 0u;
}

__global__ __launch_bounds__(NTHR, 2) void monster(MonsterArgs P)
{
    const int bid = blockIdx.x, tid = threadIdx.x;
    unsigned* bar = P.bar;
    __shared__ float smem[1120];
    float* As   = smem;
    float* Bs   = smem + 512;
    float* hbuf = smem;          // phase-local reuse
    float* red  = smem + 320;
    float* sA   = smem;

    // ================= PHASE 0: pack weights + init (independent tasks) ======
    {
        const int T0 = KP*N4P, T1 = KPP*NPPP, T2 = KOP*NPPP, T3 = Ff*NHP;
        const int total = T0 + T1 + T2 + T3 + N4P + NPPP + NHP;
        for (int idx = bid*NTHR + tid; idx < total; idx += GRIDN*NTHR) {
            int i = idx;
            if (i < T0) {
                int j = i / N4P, n = i % N4P, c = n >> 2, g = n & 3;
                float v = 0.0f;
                if (j < COMBc && n < NGATE) {
                    const float* W = (g==0)?P.Wi:(g==1)?P.Wf:(g==2)?P.Wo:P.Wg;
                    v = W[j*Hh + c];
                }
                P.W4p[i] = v; continue;
            }
            i -= T0;
            if (i < T1) {
                int j = i / NPPP, n = i % NPPP;
                float v = 0.0f;
                if (n < Hh) {
                    if (j < Ff) v = P.Wcp[j*Hh + n];
                    else if (j < Ff+Hh) v = P.Whp[(j-Ff)*Hh + n];
                }
                P.Wpp[i] = v; continue;
            }
            i -= T1;
            if (i < T2) {
                int j = i / NPPP, n = i % NPPP;
                P.Wopp[i] = (j < Hh && n < Hh) ? P.Wop[j*Hh + n] : 0.0f;
                continue;
            }
            i -= T2;
            if (i < T3) {
                int j = i / NHP, n = i % NHP, c = n >> 1, g = n & 1;
                P.Whc[i] = (c < Hh) ? (g ? P.Wc0[j*Hh + c] : P.Wh0[j*Hh + c]) : 0.0f;
                continue;
            }
            i -= T3;
            if (i < N4P) {
                int c = i >> 2, g = i & 3;
                float v = 0.0f;
                if (c < Hh) {
                    const float* bb = (g==0)?P.bi:(g==1)?P.bf:(g==2)?P.bo:P.bg;
                    v = bb[c];
                }
                P.b4[i] = v; continue;
            }
            i -= N4P;
            if (i < NPPP) { P.bp[i] = (i < Hh) ? (P.bcp[i] + P.bhp[i]) : 0.0f; continue; }
            i -= NPPP;
            { int c = i >> 1, g = i & 1;
              P.bhc[i] = (c < Hh) ? (g ? P.bc0[c] : P.bh0[c]) : 0.0f; }
        }
        // ---- meanT[f][b]: 256 blocks = (4 f-tiles of 512, 64 b) ----
        {
            const int b = bid & 63, ft = bid >> 6;
            for (int f = ft*512 + tid; f < ft*512 + 512; f += NTHR) {
                const float* pe = P.enc + (b*Cc)*Ff + f;
                float s = 0.0f;
#pragma unroll 10
                for (int c = 0; c < Cc; c++) s += pe[c*Ff];
                P.meanT[f*64 + b] = s * (1.0f/Cc);
            }
        }
        // ---- e_enc[b][c]: block = (b, c-group of 25), wave per c ----
        {
            const int b = bid & 63, cgp = bid >> 6;
            const int w = tid >> 6, lane = tid & 63;
            for (int c = cgp*25 + w; c < cgp*25 + 25; c += 4) {
                const float* p = P.enc + (b*Cc + c)*Ff;
                float s = 0.0f;
                for (int k = lane; k < Ff; k += 64) s += p[k]*P.We_enc[k];
                for (int o = 32; o; o >>= 1) s += __shfl_xor(s, o);
                if (lane == 0) P.e_enc[b*Cc + c] = s;
            }
        }
        // ---- embedding gather E[t][j][b] ----
        for (int idx = bid*NTHR + tid; idx < (Tt-1)*Hh*Bb; idx += GRIDN*NTHR) {
            const int j = idx % Hh;
            const int bt = idx / Hh;
            const int b = bt / (Tt-1), t = bt % (Tt-1);
            P.E[(t*Hh + j)*64 + b] = P.emb[(long)P.caps[b*Tt + t]*Hh + j];
        }
        // ---- out[:,0,:] = embedding[BOS] ----
        for (int idx = bid*NTHR + tid; idx < Bb*Hh; idx += GRIDN*NTHR) {
            const int b = idx / Hh, j = idx % Hh;
            P.out[(b*Tt)*Hh + j] = P.emb[(long)BOSi*Hh + j];
        }
    }
    gsync_heavy(bar);

    // ================= PHASE 1: h0/c0 GEMM (meanT @ Whc), 80 units ===========
    if (bid < 80) {
        const int ks = bid & 7, nt = bid >> 3;
        const int n0 = nt*64, k0 = ks*256;
        float acc[4][4] = {};
        auto loadA = [&](int kb, int idx) -> float {
            int j = k0 + kb*8 + (idx >> 6);
            return P.meanT[j*64 + (idx & 63)];
        };
        auto loadB = [&](int kb, int idx) -> float {
            int j = k0 + kb*8 + (idx >> 6);
            return P.Whc[j*NHP + n0 + (idx & 63)];
        };
        gemm64(32, loadA, loadB, As, Bs, acc, tid);
        const int tx = tid & 15, ty = tid >> 4;
#pragma unroll
        for (int i = 0; i < 4; i++)
            *(float4*)&P.parth[(ks*64 + ty*4 + i)*NHP + n0 + tx*4]
                = make_float4(acc[i][0], acc[i][1], acc[i][2], acc[i][3]);
    }
    gsync_heavy(bar);

    // ================= PHASE 2: h0/c0 epilogue + softmax for step 1 ==========
    if (bid < 64) {
        const int b = bid;
        for (int col = tid; col < Hh; col += NTHR) {
            float sh = P.bhc[2*col], sc = P.bhc[2*col+1];
            for (int ks = 0; ks < 8; ks++) {
                const float2 v = *(const float2*)&P.parth[(ks*64 + b)*NHP + 2*col];
                sh += v.x; sc += v.y;
            }
            float h = tanhf(sh);
            P.cst[b*Hh + col] = tanhf(sc);
            P.hT[(0*Hh + col)*64 + b] = h;
            hbuf[col] = h;
        }
        __syncthreads();
        attn_softmax2(b, 0, P.e_enc, P.We_hid, P.be[0], hbuf, red, P.attnbuf);
    }
    gsync_heavy(bar);
    // From here to loop end: NO cache invalidation. enc/W4p/E/biases stay
    // L1/L2-resident; all cross-block activations go through coherent LLC ops.

    // ================= RECURRENT LOOP ========================================
    for (int t = 1; t < Tt; t++) {
        // ---- ctx: 256 units = (4 f-tiles of 512, 64 b) ----
        {
            const int b = bid & 63, ft = bid >> 6;
            if (tid < Cc) sA[tid] = cload(&P.attnbuf[(t-1)*8192 + b*128 + tid]);
            __syncthreads();
            const int f = ft*512 + tid*2;
            const float* pe = P.enc + (b*Cc)*Ff + f;
            float2 a = make_float2(0.f, 0.f);
#pragma unroll 10
            for (int c = 0; c < Cc; c++) {
                const float w0 = sA[c];
                const float2 v = *(const float2*)&pe[c*Ff];
                a.x += w0*v.x; a.y += w0*v.y;
            }
            float* dst = P.ctxT + ((t-1)*Ff + f)*64 + b;
            cstore(&dst[0],  a.x);
            cstore(&dst[64], a.y);
            __syncthreads();
        }
        gsync_light(bar);

        // ---- gate GEMM: 247 units = (19 n-tiles, 13 k-splits of 208) ----
        if (bid < 247) {
            const int ks = bid % 13, nt = bid / 13;
            const int n0 = nt*64, k0 = ks*208;
            const float* Esrc = P.E    + (t-1)*Hh*64;
            const float* hsrc = P.hT   + (t-1)*Hh*64;
            const float* csrc = P.ctxT + (t-1)*Ff*64;
            float acc[4][4] = {};
            auto loadA = [&](int kb, int idx) -> float {
                int kk = idx >> 6, bb = idx & 63;
                int j = k0 + kb*8 + kk;
                if (j < Hh)        return Esrc[j*64 + bb];            // cached (ro)
                if (j < 2*Hh)      return cload(&hsrc[(j-Hh)*64 + bb]);
                if (j < COMBc)     return cload(&csrc[(j-2*Hh)*64 + bb]);
                return 0.0f;
            };
            auto loadB = [&](int kb, int idx) -> float {
                int j = k0 + kb*8 + (idx >> 6);
                return P.W4p[j*N4P + n0 + (idx & 63)];                // cached (ro)
            };
            gemm64(26, loadA, loadB, As, Bs, acc, tid);
            const int tx = tid & 15, ty = tid >> 4;
#pragma unroll
            for (int i = 0; i < 4; i++) {
                float* dst = &P.part[(ks*64 + ty*4 + i)*N4P + n0 + tx*4];
                cstore(&dst[0], acc[i][0]); cstore(&dst[1], acc[i][1]);
                cstore(&dst[2], acc[i][2]); cstore(&dst[3], acc[i][3]);
            }
        }
        gsync_light(bar);

        // ---- LSTM cell + softmax for next step: 64 units ----
        if (bid < 64) {
            const int b = bid;
            for (int col = tid; col < Hh; col += NTHR) {
                float4 s = ((const float4*)P.b4)[col];
                for (int ks = 0; ks < 13; ks++) {
                    const float* pp = P.part + (ks*64 + b)*N4P + col*4;
                    s.x += cload(&pp[0]); s.y += cload(&pp[1]);
                    s.z += cload(&pp[2]); s.w += cload(&pp[3]);
                }
                float ig = sigmf_(s.x), fg = sigmf_(s.y), og = sigmf_(s.z), gg = tanhf(s.w);
                float cn = fg*P.cst[b*Hh + col] + ig*gg;   // cst block-local: cached
                P.cst[b*Hh + col] = cn;
                float h = og*tanhf(cn);
                cstore(&P.hT[(t*Hh + col)*64 + b], h);
                hbuf[col] = h;
            }
            __syncthreads();
            attn_softmax2(b, t, P.e_enc, P.We_hid, P.be[0], hbuf, red, P.attnbuf);
        }
        gsync_light(bar);
    }

    gsync_heavy(bar);   // flush/invalidate once: loop activations -> cached phase

    // ================= PRED A: [ctx_t | h_t] @ [Wcp;Whp], 744 units ==========
    for (int u = bid; u < 744; u += GRIDN) {
        const int nt = u % 6, ti = (u/6) % 31, ks = u / 186;
        const int n0 = nt*64, k0 = ks*592;
        const float* csrc = P.ctxT + ti*Ff*64;
        const float* hsrc = P.hT + (ti+1)*Hh*64;
        float acc[4][4] = {};
        auto loadA = [&](int kb, int idx) -> float {
            int kk = idx >> 6, bb = idx & 63;
            int j = k0 + kb*8 + kk;
            if (j < Ff)      return csrc[j*64 + bb];
            if (j < Ff+Hh)   return hsrc[(j-Ff)*64 + bb];
            return 0.0f;
        };
        auto loadB = [&](int kb, int idx) -> float {
            int j = k0 + kb*8 + (idx >> 6);
            return P.Wpp[j*NPPP + n0 + (idx & 63)];
        };
        gemm64(74, loadA, loadB, As, Bs, acc, tid);
        const int tx = tid & 15, ty = tid >> 4;
#pragma unroll
        for (int j = 0; j < 4; j++)
            *(float4*)&P.ppart[((ks*31 + ti)*NPPP + n0 + tx*4 + j)*64 + ty*4]
                = make_float4(acc[0][j], acc[1][j], acc[2][j], acc[3][j]);
    }
    gsync_heavy(bar);

    // ================= PRED A2: reduce + emb + bias -> tmpT ==================
    for (int idx = bid*NTHR + tid; idx < 31*KOP*64; idx += GRIDN*NTHR) {
        const int ti = idx / (KOP*64);
        const int r = idx % (KOP*64);
        const int j = r / 64, b = r % 64;
        float v = 0.0f;
        if (j < Hh) {
            v = P.E[(ti*Hh + j)*64 + b] + P.bp[j];
            for (int ks = 0; ks < 4; ks++)
                v += P.ppart[((ks*31 + ti)*NPPP + j)*64 + b];
        }
        P.tmpT[idx] = v;
    }
    gsync_heavy(bar);

    // ================= PRED B: tmp @ Wop + bop -> out, 186 units =============
    if (bid < 186) {
        const int nt = bid % 6, ti = bid / 6;
        const int n0 = nt*64;
        const float* Asrc = P.tmpT + ti*KOP*64;
        float acc[4][4] = {};
        auto loadA = [&](int kb, int idx) -> float {
            int j = kb*8 + (idx >> 6);
            return Asrc[j*64 + (idx & 63)];
        };
        auto loadB = [&](int kb, int idx) -> float {
            int j = kb*8 + (idx >> 6);
            return P.Wopp[j*NPPP + n0 + (idx & 63)];
        };
        gemm64(38, loadA, loadB, As, Bs, acc, tid);
        const int tx = tid & 15, ty = tid >> 4;
#pragma unroll
        for (int i = 0; i < 4; i++) {
            const int b = ty*4 + i;
#pragma unroll
            for (int j = 0; j < 4; j++) {
                const int n = n0 + tx*4 + j;
                if (n < Hh)
                    P.out[(b*Tt + (ti+1))*Hh + n] = acc[i][j] + P.bop[n];
            }
        }
    }
}

// ---------------------------------------------------------------------------
extern "C" void kernel_launch(void* const* d_in, const int* in_sizes, int n_in,
                              void* d_out, int out_size, void* d_ws, size_t ws_size,
                              hipStream_t stream)
{
    MonsterArgs P;
    P.enc    = (const float*)d_in[0];
    P.caps   = (const int*)  d_in[1];
    P.emb    = (const float*)d_in[2];
    P.Wh0    = (const float*)d_in[3];
    P.bh0    = (const float*)d_in[4];
    P.Wc0    = (const float*)d_in[5];
    P.bc0    = (const float*)d_in[6];
    P.We_enc = (const float*)d_in[7];
    P.We_hid = (const float*)d_in[8];
    P.be     = (const float*)d_in[9];
    P.Wi     = (const float*)d_in[10];
    P.bi     = (const float*)d_in[11];
    P.Wf     = (const float*)d_in[12];
    P.bf     = (const float*)d_in[13];
    P.Wo     = (const float*)d_in[14];
    P.bo     = (const float*)d_in[15];
    P.Wg     = (const float*)d_in[16];
    P.bg     = (const float*)d_in[17];
    P.Wcp    = (const float*)d_in[18];
    P.bcp    = (const float*)d_in[19];
    P.Whp    = (const float*)d_in[20];
    P.bhp    = (const float*)d_in[21];
    P.Wop    = (const float*)d_in[22];
    P.bop    = (const float*)d_in[23];
    P.out    = (float*)d_out;

    float* w = (float*)d_ws;
    P.bar   = (unsigned*)w; w += 64;     // barrier state (own cacheline)
    P.W4p   = w; w += KP*N4P;        // 3,288,064
    P.Wpp   = w; w += KPP*NPPP;      //   909,312
    P.Wopp  = w; w += KOP*NPPP;      //   116,736
    P.b4    = w; w += N4P;
    P.bp    = w; w += NPPP;
    P.bhc   = w; w += NHP;
    P.e_enc = w; w += Bb*Cc;
    P.hT    = w; w += Tt*Hh*64;      //   614,400
    P.ctxT  = w; w += (Tt-1)*Ff*64;  // 4,063,232
    P.E     = w; w += (Tt-1)*Hh*64;  //   595,200
    P.cst   = w; w += Bb*Hh;
    P.attnbuf = w; w += Tt*64*128;   //   262,144
    P.part  = w; w += 16*Bb*N4P;     // 1,245,184  (13 used; parth aliases pre-loop)
    P.ppart = w; w += 4*31*NPPP*64;  // 3,047,424  (Whc aliases: used only pre-loop)
    P.tmpT  = w; w += 31*KOP*64;     //   603,136  (meanT aliases: used only pre-loop)
    P.parth = P.part;                // 8*64*640 = 327,680 <= part
    P.Whc   = P.ppart;               // 2048*640 = 1,310,720 <= ppart
    P.meanT = P.tmpT;                // 2048*64  = 131,072 <= tmpT
    (void)ws_size; (void)in_sizes; (void)n_in; (void)out_size;

    k_zero<<<1, 64, 0, stream>>>(P.bar);
    monster<<<GRIDN, NTHR, 0, stream>>>(P);
}

// Round 6
// 3545.443 us; speedup vs baseline: 2.5939x; 1.0380x over previous
//
#include <hip/hip_runtime.h>
#include <math.h>

// Problem constants
#define Bb    64
#define Cc    100
#define Ff    2048
#define Tt    32
#define Hh    300
#define COMBc 2648
#define ROWC  2704            // comb row stride (13*208, 8B aligned)
#define SLOT  (64*ROWC)
#define N4P   1216            // 4*H padded to 38*32
#define NGATE 1200
#define KPP   2368            // 2048+300 padded to 2*1184 (74*16 each)
#define NPPP  384
#define KOP   304
#define NHP   640
#define CSTSZ (64*304)
#define BOSi  1
#define GRIDN 512
#define NTHR  256

__device__ __forceinline__ float sigmf_(float x){ return 1.0f/(1.0f + expf(-x)); }

// Coherent (agent-scope) accessors: bypass non-coherent per-XCD L2, serviced
// at the coherence point. 8-byte wide + wave-contiguous addressing = full
// 64B-line utilization (round-5 lesson: scalar strided cload/cstore caused
// ~16x line amplification).
__device__ __forceinline__ float cload(const float* p){
    return __hip_atomic_load(p, __ATOMIC_RELAXED, __HIP_MEMORY_SCOPE_AGENT);
}
__device__ __forceinline__ void cstore(float* p, float v){
    __hip_atomic_store(p, v, __ATOMIC_RELAXED, __HIP_MEMORY_SCOPE_AGENT);
}
__device__ __forceinline__ float2 cload2(const float* p){
    union { unsigned long long u; float2 f; } c;
    c.u = __hip_atomic_load((const unsigned long long*)p, __ATOMIC_RELAXED, __HIP_MEMORY_SCOPE_AGENT);
    return c.f;
}
__device__ __forceinline__ void cstore2(float* p, float2 v){
    union { float2 f; unsigned long long u; } c; c.f = v;
    __hip_atomic_store((unsigned long long*)p, c.u, __ATOMIC_RELAXED, __HIP_MEMORY_SCOPE_AGENT);
}

__device__ __forceinline__ void fma16_(const float4 av, const float4 bv, float acc[4][4]){
    acc[0][0] += av.x*bv.x; acc[0][1] += av.x*bv.y; acc[0][2] += av.x*bv.z; acc[0][3] += av.x*bv.w;
    acc[1][0] += av.y*bv.x; acc[1][1] += av.y*bv.y; acc[1][2] += av.y*bv.z; acc[1][3] += av.y*bv.w;
    acc[2][0] += av.z*bv.x; acc[2][1] += av.z*bv.y; acc[2][2] += av.z*bv.z; acc[2][3] += av.z*bv.w;
    acc[3][0] += av.w*bv.x; acc[3][1] += av.w*bv.y; acc[3][2] += av.w*bv.z; acc[3][3] += av.w*bv.w;
}

// Monotonic-counter grid barrier (no reset -> no reset race). RELEASE on
// arrival orders prior stores; spin is RELAXED (no cache-invalidate storm).
// heavy=true adds full fences for bulk cached-data ownership transfer.
__device__ __forceinline__ void gsync(unsigned* bar, unsigned target, bool heavy)
{
    __syncthreads();
    if (threadIdx.x == 0) {
        if (heavy) __threadfence();
        __hip_atomic_fetch_add(&bar[0], 1u, __ATOMIC_RELEASE, __HIP_MEMORY_SCOPE_AGENT);
        while (__hip_atomic_load(&bar[0], __ATOMIC_RELAXED, __HIP_MEMORY_SCOPE_AGENT) < target)
            __builtin_amdgcn_s_sleep(4);
        if (heavy) __threadfence();
    }
    __syncthreads();
}

// ---------------------------------------------------------------------------
// Old-style 64xN GEMM tile, A in k-major [j][b] layout, 8-row stages.
// Used for h0 GEMM (meanT) and predb (tmpT): cached plain loads.
// ---------------------------------------------------------------------------
template <typename LA, typename LB>
__device__ __forceinline__ void gemm64(int KB, LA loadA, LB loadB,
                                       float* As, float* Bs, float acc[4][4], int tid)
{
    const int tx = tid & 15, ty = tid >> 4;
    float a0 = loadA(0, tid), a1 = loadA(0, tid + 256);
    float b0 = loadB(0, tid), b1 = loadB(0, tid + 256);
    for (int kb = 0; kb < KB; kb++) {
        __syncthreads();
        As[tid] = a0; As[tid + 256] = a1;
        Bs[tid] = b0; Bs[tid + 256] = b1;
        __syncthreads();
        if (kb + 1 < KB) {
            a0 = loadA(kb+1, tid); a1 = loadA(kb+1, tid + 256);
            b0 = loadB(kb+1, tid); b1 = loadB(kb+1, tid + 256);
        }
#pragma unroll
        for (int kk = 0; kk < 8; kk++) {
            float4 av = *(const float4*)&As[kk*64 + ty*4];
            float4 bv = *(const float4*)&Bs[kk*64 + tx*4];
            fma16_(av, bv, acc);
        }
    }
}

// ---------------------------------------------------------------------------
// Transposing GEMM tiles: A source is b-major [b][j] (comb layout); lanes load
// contiguous float2 runs and deposit transposed into LDS As[16][68] (pad 68
// breaks the 8-way write conflict). 16-row K stages.
// la(kb, bb, kp) -> float2 of A[bb][k0+kb*16+kp*2 .. +1]
// ---------------------------------------------------------------------------
template <typename LA2, typename LB>
__device__ __forceinline__ void gemmT32(int KB, LA2 la, LB lb, float* As, float* Bs,
                                        float acc[4][2], int tid)
{
    const int tx = tid & 15, ty = tid >> 4;
    const int bb = tid >> 3, kp = tid & 7;
    float2 a0 = la(0, bb, kp), a1 = la(0, bb+32, kp);
    float b0 = lb(0, tid), b1 = lb(0, tid+256);
    for (int kb = 0; kb < KB; kb++) {
        __syncthreads();
        As[(kp*2  )*68 + bb   ] = a0.x; As[(kp*2+1)*68 + bb   ] = a0.y;
        As[(kp*2  )*68 + bb+32] = a1.x; As[(kp*2+1)*68 + bb+32] = a1.y;
        Bs[tid] = b0; Bs[tid+256] = b1;
        __syncthreads();
        if (kb+1 < KB) {
            a0 = la(kb+1, bb, kp); a1 = la(kb+1, bb+32, kp);
            b0 = lb(kb+1, tid); b1 = lb(kb+1, tid+256);
        }
#pragma unroll
        for (int kk = 0; kk < 16; kk++) {
            float4 av = *(const float4*)&As[kk*68 + ty*4];
            float2 bv = *(const float2*)&Bs[kk*32 + tx*2];
            acc[0][0]+=av.x*bv.x; acc[0][1]+=av.x*bv.y;
            acc[1][0]+=av.y*bv.x; acc[1][1]+=av.y*bv.y;
            acc[2][0]+=av.z*bv.x; acc[2][1]+=av.z*bv.y;
            acc[3][0]+=av.w*bv.x; acc[3][1]+=av.w*bv.y;
        }
    }
}

template <typename LA2, typename LB>
__device__ __forceinline__ void gemmT64(int KB, LA2 la, LB lb, float* As, float* Bs,
                                        float acc[4][4], int tid)
{
    const int tx = tid & 15, ty = tid >> 4;
    const int bb = tid >> 3, kp = tid & 7;
    float2 a0 = la(0, bb, kp), a1 = la(0, bb+32, kp);
    float b0 = lb(0, tid), b1 = lb(0, tid+256), b2 = lb(0, tid+512), b3 = lb(0, tid+768);
    for (int kb = 0; kb < KB; kb++) {
        __syncthreads();
        As[(kp*2  )*68 + bb   ] = a0.x; As[(kp*2+1)*68 + bb   ] = a0.y;
        As[(kp*2  )*68 + bb+32] = a1.x; As[(kp*2+1)*68 + bb+32] = a1.y;
        Bs[tid] = b0; Bs[tid+256] = b1; Bs[tid+512] = b2; Bs[tid+768] = b3;
        __syncthreads();
        if (kb+1 < KB) {
            a0 = la(kb+1, bb, kp); a1 = la(kb+1, bb+32, kp);
            b0 = lb(kb+1, tid); b1 = lb(kb+1, tid+256);
            b2 = lb(kb+1, tid+512); b3 = lb(kb+1, tid+768);
        }
#pragma unroll
        for (int kk = 0; kk < 16; kk++) {
            float4 av = *(const float4*)&As[kk*68 + ty*4];
            float4 bv = *(const float4*)&Bs[kk*64 + tx*4];
            fma16_(av, bv, acc);
        }
    }
}

struct MonsterArgs {
    const float *enc, *emb; const int* caps;
    const float *Wh0,*bh0,*Wc0,*bc0,*We_enc,*We_hid,*be;
    const float *Wi,*bi,*Wf,*bf,*Wo,*bo,*Wg,*bg;
    const float *Wcp,*bcp,*Whp,*bhp,*Wop,*bop;
    float* out;
    float *W4p,*Wpp,*Wopp,*Whc,*b4,*bp,*bhc,*e_enc,*cst,*comb,
          *part,*parth,*ppart,*tmpT,*meanT;
    unsigned* bar;
};

__global__ void k_zero(unsigned* bar)
{
    if (threadIdx.x < 16) bar[threadIdx.x] = 0u;
}

// softmax(h) for block's b into sA, then optional ctx f-tile -> comb[slot][b][600+f].
__device__ __forceinline__ void softmax_ctx(const MonsterArgs& P, int b, int ft, int slot,
                                            bool do_ctx, float* hbuf, float* red, float* sA)
{
    const int tid = threadIdx.x;
    float p = hbuf[tid]*P.We_hid[tid];
    if (tid < 44) p += hbuf[tid+256]*P.We_hid[tid+256];
    red[tid] = p;
    __syncthreads();
    for (int s = 128; s > 0; s >>= 1) { if (tid < s) red[tid] += red[tid+s]; __syncthreads(); }
    const float eh = red[0] + P.be[0];
    if (tid < 64) {
        float v0 = P.e_enc[b*Cc + tid] + eh;
        float v1 = (tid+64 < Cc) ? (P.e_enc[b*Cc + tid+64] + eh) : -1e30f;
        float m = fmaxf(v0, v1);
        for (int o = 32; o; o >>= 1) m = fmaxf(m, __shfl_xor(m, o));
        float e0 = expf(v0-m), e1 = (tid+64<Cc)?expf(v1-m):0.0f;
        float s = e0+e1;
        for (int o = 32; o; o >>= 1) s += __shfl_xor(s, o);
        float inv = 1.0f/s;
        sA[tid] = e0*inv; sA[tid+64] = e1*inv;
    }
    __syncthreads();
    if (do_ctx) {
        const int f = ft*512 + tid*2;
        const float* pe = P.enc + (b*Cc)*Ff + f;
        float2 a = make_float2(0.f, 0.f);
#pragma unroll 10
        for (int c = 0; c < Cc; c++) {
            const float w0 = sA[c];
            const float2 v = *(const float2*)&pe[c*Ff];
            a.x += w0*v.x; a.y += w0*v.y;
        }
        cstore2(&P.comb[slot*SLOT + b*ROWC + 600 + f], a);
    }
    __syncthreads();
}

__global__ __launch_bounds__(NTHR, 2) void monster(MonsterArgs P)
{
    const int bid = blockIdx.x, tid = threadIdx.x;
    unsigned* bar = P.bar;
    unsigned bt = 0;
    __shared__ float smem[2112];
    float* As   = smem;                // gemmT: [16][68]=1088 ; gemm64: [8][64]=512
    float* BsT  = smem + 1088;         // gemmT: up to [16][64]=1024
    float* Bs8  = smem + 512;          // gemm64
    float* hbuf = smem;                // fused-phase reuse
    float* red  = smem + 304;
    float* sA   = smem + 560;

    // ================= PHASE 0: pack weights + init ==========================
    {
        const int T0 = ROWC*N4P, T1 = KPP*NPPP, T2 = KOP*NPPP, T3 = Ff*NHP;
        const int total = T0 + T1 + T2 + T3 + N4P + NPPP + NHP;
        for (int idx = bid*NTHR + tid; idx < total; idx += GRIDN*NTHR) {
            int i = idx;
            if (i < T0) {
                int j = i / N4P, n = i % N4P, c = n >> 2, g = n & 3;
                float v = 0.0f;
                if (j < COMBc && n < NGATE) {
                    const float* W = (g==0)?P.Wi:(g==1)?P.Wf:(g==2)?P.Wo:P.Wg;
                    v = W[j*Hh + c];
                }
                P.W4p[i] = v; continue;
            }
            i -= T0;
            if (i < T1) {
                int j = i / NPPP, n = i % NPPP;
                float v = 0.0f;
                if (n < Hh) {
                    if (j < Ff) v = P.Wcp[j*Hh + n];
                    else if (j < Ff+Hh) v = P.Whp[(j-Ff)*Hh + n];
                }
                P.Wpp[i] = v; continue;
            }
            i -= T1;
            if (i < T2) {
                int j = i / NPPP, n = i % NPPP;
                P.Wopp[i] = (j < Hh && n < Hh) ? P.Wop[j*Hh + n] : 0.0f;
                continue;
            }
            i -= T2;
            if (i < T3) {
                int j = i / NHP, n = i % NHP, c = n >> 1, g = n & 1;
                P.Whc[i] = (c < Hh) ? (g ? P.Wc0[j*Hh + c] : P.Wh0[j*Hh + c]) : 0.0f;
                continue;
            }
            i -= T3;
            if (i < N4P) {
                int c = i >> 2, g = i & 3;
                float v = 0.0f;
                if (c < Hh) {
                    const float* bb2 = (g==0)?P.bi:(g==1)?P.bf:(g==2)?P.bo:P.bg;
                    v = bb2[c];
                }
                P.b4[i] = v; continue;
            }
            i -= N4P;
            if (i < NPPP) { P.bp[i] = (i < Hh) ? (P.bcp[i] + P.bhp[i]) : 0.0f; continue; }
            i -= NPPP;
            { int c = i >> 1, g = i & 1;
              P.bhc[i] = (c < Hh) ? (g ? P.bc0[c] : P.bh0[c]) : 0.0f; }
        }
        // meanT[f][b] (k-major): 512 blocks = (8 ftiles of 256, 64 b)
        {
            const int b = bid & 63, ft = bid >> 6;
            const int f = ft*256 + tid;
            const float* pe = P.enc + (b*Cc)*Ff + f;
            float s = 0.0f;
#pragma unroll 10
            for (int c = 0; c < Cc; c++) s += pe[c*Ff];
            P.meanT[f*64 + b] = s * (1.0f/Cc);
        }
        // e_enc[b][c]
        {
            const int b = bid & 63, grp = bid >> 6;
            const int w = tid >> 6, lane = tid & 63;
            const int cend = min(Cc, grp*13 + 13);
            for (int c = grp*13 + w; c < cend; c += 4) {
                const float* p = P.enc + (b*Cc + c)*Ff;
                float s = 0.0f;
                for (int k = lane; k < Ff; k += 64) s += p[k]*P.We_enc[k];
                for (int o = 32; o; o >>= 1) s += __shfl_xor(s, o);
                if (lane == 0) P.e_enc[b*Cc + c] = s;
            }
        }
        // E region of comb: comb[s][b][0:300] = emb[caps[b][s]], s=0..30
        for (int idx = bid*NTHR + tid; idx < 31*Bb*Hh; idx += GRIDN*NTHR) {
            const int j = idx % Hh;
            const int r = idx / Hh;
            const int b = r % Bb, s = r / Bb;
            P.comb[s*SLOT + b*ROWC + j] = P.emb[(long)P.caps[b*Tt + s]*Hh + j];
        }
        // zero comb rows [2648,2704) for slots 0..30 (gate GEMM overreach)
        for (int idx = bid*NTHR + tid; idx < 31*Bb*(ROWC-COMBc); idx += GRIDN*NTHR) {
            const int q = idx % (ROWC-COMBc);
            const int r = idx / (ROWC-COMBc);
            const int b = r % Bb, s = r / Bb;
            P.comb[s*SLOT + b*ROWC + COMBc + q] = 0.0f;
        }
        // out[:,0,:] = embedding[BOS]
        for (int idx = bid*NTHR + tid; idx < Bb*Hh; idx += GRIDN*NTHR) {
            const int b = idx / Hh, j = idx % Hh;
            P.out[(b*Tt)*Hh + j] = P.emb[(long)BOSi*Hh + j];
        }
    }
    bt += GRIDN; gsync(bar, bt, true);    // HEAVY: bulk plain -> cached handoff

    // ================= PHASE 1: h0/c0 GEMM (meanT @ Whc), 80 units ===========
    if (bid < 80) {
        const int ks = bid & 7, nt = bid >> 3;
        const int n0 = nt*64, k0 = ks*256;
        float acc[4][4] = {};
        auto loadA = [&](int kb, int idx) -> float {
            int j = k0 + kb*8 + (idx >> 6);
            return P.meanT[j*64 + (idx & 63)];
        };
        auto loadB = [&](int kb, int idx) -> float {
            int j = k0 + kb*8 + (idx >> 6);
            return P.Whc[j*NHP + n0 + (idx & 63)];
        };
        gemm64(32, loadA, loadB, As, Bs8, acc, tid);
        const int tx = tid & 15, ty = tid >> 4;
#pragma unroll
        for (int i = 0; i < 4; i++) {
            float* dst = &P.parth[(ks*64 + ty*4 + i)*NHP + n0 + tx*4];
            cstore2(dst,   make_float2(acc[i][0], acc[i][1]));
            cstore2(dst+2, make_float2(acc[i][2], acc[i][3]));
        }
    }
    bt += GRIDN; gsync(bar, bt, false);

    // ================= PHASE 2: h0/c0 epilogue + softmax + ctx_1 (fused) =====
    if (bid < 256) {
        const int b = bid & 63, ft = bid >> 6;
        float* cstW = P.cst;                         // buffer 0 (read at t=1)
        for (int col = tid; col < Hh; col += NTHR) {
            float sh = P.bhc[2*col], sc = P.bhc[2*col+1];
            for (int ks = 0; ks < 8; ks++) {
                const float2 v = cload2(&P.parth[(ks*64 + b)*NHP + 2*col]);
                sh += v.x; sc += v.y;
            }
            float h = tanhf(sh);
            cstore(&cstW[b*304 + col], tanhf(sc));
            cstore(&P.comb[0*SLOT + b*ROWC + 300 + col], h);
            hbuf[col] = h;
        }
        __syncthreads();
        softmax_ctx(P, b, ft, 0, true, hbuf, red, sA);
    }
    bt += GRIDN; gsync(bar, bt, false);

    // ================= RECURRENT LOOP ========================================
    for (int t = 1; t < Tt; t++) {
        // ---- Phase G: gate GEMM, 494 units = (38 n-tiles of 32, 13 k-splits)
        if (bid < 494) {
            const int nt = bid / 13, ks = bid % 13;
            const int n0 = nt*32, k0 = ks*208;
            const float* Asrc = P.comb + (t-1)*SLOT;
            float acc[4][2] = {};
            auto la = [&](int kb, int bb2, int kp) -> float2 {
                return cload2(&Asrc[bb2*ROWC + k0 + kb*16 + kp*2]);
            };
            auto lb = [&](int kb, int idx) -> float {
                return P.W4p[(k0 + kb*16 + (idx >> 5))*N4P + n0 + (idx & 31)];
            };
            gemmT32(13, la, lb, As, BsT, acc, tid);
            const int tx = tid & 15, ty = tid >> 4;
#pragma unroll
            for (int i = 0; i < 4; i++)
                cstore2(&P.part[(ks*64 + ty*4 + i)*N4P + n0 + tx*2],
                        make_float2(acc[i][0], acc[i][1]));
        }
        bt += GRIDN; gsync(bar, bt, false);

        // ---- Phase L: LSTM (x4 dup) + softmax + ctx_{t+1}, 256 units --------
        if (bid < 256) {
            const int b = bid & 63, ft = bid >> 6;
            const float* cstR = P.cst + ((t-1)&1)*CSTSZ;
            float*       cstW = P.cst + (t&1)*CSTSZ;
            for (int col = tid; col < Hh; col += NTHR) {
                float4 s = ((const float4*)P.b4)[col];
                for (int ks = 0; ks < 13; ks++) {
                    const float* pp = P.part + (ks*64 + b)*N4P + col*4;
                    const float2 v01 = cload2(pp), v23 = cload2(pp+2);
                    s.x += v01.x; s.y += v01.y; s.z += v23.x; s.w += v23.y;
                }
                float ig = sigmf_(s.x), fg = sigmf_(s.y), og = sigmf_(s.z), gg = tanhf(s.w);
                float cn = fg*cload(&cstR[b*304 + col]) + ig*gg;
                cstore(&cstW[b*304 + col], cn);
                float h = og*tanhf(cn);
                cstore(&P.comb[t*SLOT + b*ROWC + 300 + col], h);
                hbuf[col] = h;
            }
            __syncthreads();
            softmax_ctx(P, b, ft, t, t < Tt-1, hbuf, red, sA);
        }
        bt += GRIDN; gsync(bar, bt, t == Tt-1);   // heavy on loop exit
    }

    // ================= PRED A: [ctx|h] @ [Wcp;Whp], 372 units ================
    if (bid < 372) {
        const int nt = bid % 6, ti = (bid/6) % 31, ks2 = bid / 186;
        const int n0 = nt*64, k0 = ks2*1184;
        const float* c0p = P.comb + ti*SLOT;
        const float* h0p = P.comb + (ti+1)*SLOT;
        float acc[4][4] = {};
        auto la = [&](int kb, int bb2, int kp) -> float2 {
            int j = k0 + kb*16 + kp*2;
            if (j < 2048) return *(const float2*)&c0p[bb2*ROWC + 600 + j];
            return *(const float2*)&h0p[bb2*ROWC + 300 + (j - 2048)];
        };
        auto lb = [&](int kb, int idx) -> float {
            return P.Wpp[(k0 + kb*16 + (idx >> 6))*NPPP + n0 + (idx & 63)];
        };
        gemmT64(74, la, lb, As, BsT, acc, tid);
        const int tx = tid & 15, ty = tid >> 4;
#pragma unroll
        for (int j4 = 0; j4 < 4; j4++)
            *(float4*)&P.ppart[((ks2*31 + ti)*NPPP + n0 + tx*4 + j4)*64 + ty*4]
                = make_float4(acc[0][j4], acc[1][j4], acc[2][j4], acc[3][j4]);
    }
    bt += GRIDN; gsync(bar, bt, true);

    // ================= PRED A2: reduce + emb + bias -> tmpT (k-major) ========
    for (int idx = bid*NTHR + tid; idx < 31*KOP*64; idx += GRIDN*NTHR) {
        const int ti = idx / (KOP*64);
        const int r = idx % (KOP*64);
        const int j = r / 64, b = r % 64;
        float v = 0.0f;
        if (j < Hh) {
            v = P.comb[ti*SLOT + b*ROWC + j] + P.bp[j];
            v += P.ppart[((0*31 + ti)*NPPP + j)*64 + b];
            v += P.ppart[((1*31 + ti)*NPPP + j)*64 + b];
        }
        P.tmpT[idx] = v;
    }
    bt += GRIDN; gsync(bar, bt, true);

    // ================= PRED B: tmp @ Wop + bop -> out, 186 units =============
    if (bid < 186) {
        const int nt = bid % 6, ti = bid / 6;
        const int n0 = nt*64;
        const float* Asrc = P.tmpT + ti*KOP*64;
        float acc[4][4] = {};
        auto loadA = [&](int kb, int idx) -> float {
            return Asrc[(kb*8 + (idx >> 6))*64 + (idx & 63)];
        };
        auto loadB = [&](int kb, int idx) -> float {
            return P.Wopp[(kb*8 + (idx >> 6))*NPPP + n0 + (idx & 63)];
        };
        gemm64(38, loadA, loadB, As, Bs8, acc, tid);
        const int tx = tid & 15, ty = tid >> 4;
#pragma unroll
        for (int i = 0; i < 4; i++) {
            const int b = ty*4 + i;
#pragma unroll
            for (int j = 0; j < 4; j++) {
                const int n = n0 + tx*4 + j;
                if (n < Hh)
                    P.out[(b*Tt + (ti+1))*Hh + n] = acc[i][j] + P.bop[n];
            }
        }
    }
}

// ---------------------------------------------------------------------------
extern "C" void kernel_launch(void* const* d_in, const int* in_sizes, int n_in,
                              void* d_out, int out_size, void* d_ws, size_t ws_size,
                              hipStream_t stream)
{
    MonsterArgs P;
    P.enc    = (const float*)d_in[0];
    P.caps   = (const int*)  d_in[1];
    P.emb    = (const float*)d_in[2];
    P.Wh0    = (const float*)d_in[3];
    P.bh0    = (const float*)d_in[4];
    P.Wc0    = (const float*)d_in[5];
    P.bc0    = (const float*)d_in[6];
    P.We_enc = (const float*)d_in[7];
    P.We_hid = (const float*)d_in[8];
    P.be     = (const float*)d_in[9];
    P.Wi     = (const float*)d_in[10];
    P.bi     = (const float*)d_in[11];
    P.Wf     = (const float*)d_in[12];
    P.bf     = (const float*)d_in[13];
    P.Wo     = (const float*)d_in[14];
    P.bo     = (const float*)d_in[15];
    P.Wg     = (const float*)d_in[16];
    P.bg     = (const float*)d_in[17];
    P.Wcp    = (const float*)d_in[18];
    P.bcp    = (const float*)d_in[19];
    P.Whp    = (const float*)d_in[20];
    P.bhp    = (const float*)d_in[21];
    P.Wop    = (const float*)d_in[22];
    P.bop    = (const float*)d_in[23];
    P.out    = (float*)d_out;

    float* w = (float*)d_ws;
    P.bar   = (unsigned*)w; w += 64;
    P.W4p   = w; w += ROWC*N4P;       // 3,288,064
    P.Wpp   = w; w += KPP*NPPP;       //   909,312
    P.Wopp  = w; w += KOP*NPPP;       //   116,736
    P.b4    = w; w += N4P;
    P.bp    = w; w += NPPP;
    P.bhc   = w; w += NHP;
    P.e_enc = w; w += Bb*Cc;
    P.cst   = w; w += 2*CSTSZ;        //    38,912 (ping-pong)
    P.comb  = w; w += 32*SLOT;        // 5,537,792  [t][b][E|h|ctx|pad]
    P.part  = w; w += 13*Bb*N4P;      // 1,011,712
    P.ppart = w; w += 2*31*NPPP*64;   // 1,523,712
    // init/pred-phase aliases (temporally disjoint)
    P.meanT = P.part;                 //   131,072, pre-loop
    P.parth = P.part + 262144;        //   327,680, pre-loop
    P.tmpT  = P.part;                 //   603,136, post-loop
    P.Whc   = P.ppart;                // 1,310,720, pre-loop
    (void)ws_size; (void)in_sizes; (void)n_in; (void)out_size;

    k_zero<<<1, 64, 0, stream>>>(P.bar);
    monster<<<GRIDN, NTHR, 0, stream>>>(P);
}